// Round 11
// baseline (114.438 us; speedup 1.0000x reference)
//
#include <hip/hip_runtime.h>

#define NB 8192
#define ND 256
#define NH 512
#define NO 64
#define NK 8
#define TB 32
#define TILES_MAX 48   // cnt ~ 1024±30; 48*32=1536 rows headroom

// LDS byte map (144KB): xs[32][256]bf16 @0 (stride 512B); h0[32][512] @16K (stride 1024B);
// h1[32][512] @48K; W double-buffer 2x32KB @80K (L2 uses the full 64KB once).
#define XSB 0
#define H0B 16384
#define H1B 49152
#define WBB 81920

typedef unsigned short u16;
using bf16x8 = __attribute__((ext_vector_type(8))) short;
using u16x8  = __attribute__((ext_vector_type(8))) unsigned short;
using f32x4  = __attribute__((ext_vector_type(4))) float;

typedef __attribute__((address_space(1))) const unsigned char ga_u8;
typedef __attribute__((address_space(3))) unsigned char ls_u8;

__device__ __forceinline__ void gload16(const u16* g, u16* l) {
    // lane i writes lds_base + i*16; global src is per-lane (g + lane offsets baked in)
    __builtin_amdgcn_global_load_lds((ga_u8*)g, (ls_u8*)l, 16, 0, 0);
}

__device__ __forceinline__ u16 bf16rne(float f) {
    unsigned u = __float_as_uint(f);
    return (u16)((u + 0x7FFFu + ((u >> 16) & 1u)) >> 16);
}

__device__ __forceinline__ float fast_tanh(float v) {
    float a = fabsf(v);
    float e = __expf(-2.0f * a);
    float t = (1.0f - e) * __builtin_amdgcn_rcpf(1.0f + e);
    return copysignf(t, v);
}

// ws layout (bytes):
//   [0, 32)        : int cnt[8]            (memset to 0 each call)
//   [64, ~256KB)   : int bucket[8][8192]
//   [0.5MB, 2.5MB) : u16 W0F[8][8][32][64][8]    [e][kt][nt][lane][8k]
//   [2.5MB, 6.5MB) : u16 W1F[8][16][32][64][8]
//   [6.5MB, 7.0MB) : u16 WoF[8][16][4][64][8]
// Fragment (kt,nt,lane,i) = W[k = kt*32 + (lane>>4)*8 + i][n = nt*16 + (lane&15)]

// ---------------- prep: slab-coalesced fragment packing (320 blocks) + router (32) ----------------
__global__ __launch_bounds__(256) void prep_kernel(
    const float* __restrict__ x,
    const float* __restrict__ W0, const float* __restrict__ W1, const float* __restrict__ Wo,
    int* __restrict__ wsI, u16* __restrict__ W0F, u16* __restrict__ W1F, u16* __restrict__ WoF) {
    const int bid = blockIdx.x, t = threadIdx.x;
    if (bid >= 320) {                        // router: 32 blocks x 256
        __shared__ int lc[NK], lbase[NK];
        if (t < NK) lc[t] = 0;
        __syncthreads();
        const int b = (bid - 320) * 256 + t;
        const float v = x[(size_t)b * ND + 7];
        const int e = ((int)fabsf(v * 100.0f)) & (NK - 1);
        const int slot = atomicAdd(&lc[e], 1);
        __syncthreads();
        if (t < NK) lbase[t] = atomicAdd(&wsI[t], lc[t]);
        __syncthreads();
        wsI[16 + e * NB + lbase[e] + slot] = b;
        return;
    }
    __shared__ u16 slab[32 * 524];           // stride 524 u16 (1048B)
    const float* src; u16* dst; int C, NT, sh;
    if (bid < 64) {          // W0: K=256 -> 8 slabs/expert
        int e = bid >> 3, kt = bid & 7; C = NH; NT = 32; sh = 7;
        src = W0 + ((size_t)e * ND + kt * 32) * NH;
        dst = W0F + (size_t)(e * 8 + kt) * 32 * 512;
    } else if (bid < 192) {  // W1: K=512 -> 16 slabs/expert
        int i = bid - 64, e = i >> 4, kt = i & 15; C = NH; NT = 32; sh = 7;
        src = W1 + ((size_t)e * NH + kt * 32) * NH;
        dst = W1F + (size_t)(e * 16 + kt) * 32 * 512;
    } else {                 // Wo: K=512 -> 16 slabs/expert (32x64 each)
        int i = bid - 192, e = i >> 4, kt = i & 15; C = NO; NT = 4; sh = 4;
        src = Wo + ((size_t)e * NH + kt * 32) * NO;
        dst = WoF + (size_t)(e * 16 + kt) * 4 * 512;
    }
    const int c4 = C >> 2, total4 = 8 * C;
    for (int f = t; f < total4; f += 256) {
        float4 v = *(const float4*)(src + ((size_t)f << 2));
        ushort4 h;
        h.x = bf16rne(v.x); h.y = bf16rne(v.y); h.z = bf16rne(v.z); h.w = bf16rne(v.w);
        int row = f >> sh, col4 = f & (c4 - 1);
        *(ushort4*)&slab[row * 524 + col4 * 4] = h;
    }
    __syncthreads();
    for (int f = t; f < NT * 64; f += 256) {
        const int lane = f & 63, nt = f >> 6;
        const int kloc = (lane >> 4) << 3, nc = nt * 16 + (lane & 15);
        u16x8 fr;
#pragma unroll
        for (int q = 0; q < 8; ++q) fr[q] = slab[(kloc + q) * 524 + nc];
        *(u16x8*)(dst + (size_t)f * 8) = fr;
    }
}

// ---------------- fused MLP: 32 rows, 16 waves, global_load_lds double-buffered weights ----------------
__global__ __launch_bounds__(1024, 4) void mlp_kernel(
    const float* __restrict__ x,
    const float* __restrict__ b0, const float* __restrict__ b1, const float* __restrict__ bo,
    const int* __restrict__ wsI,
    const u16* __restrict__ W0F, const u16* __restrict__ W1F, const u16* __restrict__ WoF,
    float* __restrict__ out) {
    const int e = blockIdx.x & (NK - 1);
    const int tile = blockIdx.x >> 3;
    const int cnt = wsI[e];
    if (tile * TB >= cnt) return;

    __shared__ u16 L[73728];                 // 144KB
    __shared__ int rows_s[TB];
    const int t = threadIdx.x;
    const int wid = t >> 6, l = t & 63;
    const int lrow = l & 15, lkb = (l >> 4) * 16, swz = (lrow & 7) << 4;
    const int koff0 = tile & 7, koff1 = tile & 15;

    const int* bucket = wsI + 16 + e * NB;
    if (t < TB) {
        int lr = tile * TB + t;
        rows_s[t] = (lr < cnt) ? bucket[lr] : -1;
    }
    __syncthreads();

    // issue W0 slab(koff0) DMA into WB0 (latency hides under x staging)
    {
        const u16* src = W0F + (size_t)(e * 8 + koff0) * 16384;
#pragma unroll
        for (int q = 0; q < 2; ++q) {
            int c = wid * 2 + q;
            gload16(src + c * 512 + l * 8, L + ((WBB + c * 1024) >> 1));
        }
    }
    // stage x rows -> xs plane
#pragma unroll
    for (int s = 0; s < 2; ++s) {
        int i = t + s * 1024;
        int row = i >> 6, d4 = i & 63;
        int g = rows_s[row];
        float4 v = (g >= 0) ? *(const float4*)(x + (size_t)g * ND + d4 * 4)
                            : make_float4(0.f, 0.f, 0.f, 0.f);
        ushort4 h;
        h.x = bf16rne(v.x); h.y = bf16rne(v.y); h.z = bf16rne(v.z); h.w = bf16rne(v.w);
        int bb = (row * 512 + d4 * 8) ^ ((row & 7) << 4);
        *(ushort4*)&L[bb >> 1] = h;
    }
    __syncthreads();                          // xs ready + slab0 drained (vmcnt0 at barrier)

    f32x4 acc[2][2];
#pragma unroll
    for (int m = 0; m < 2; ++m)
#pragma unroll
        for (int j = 0; j < 2; ++j) acc[j][m] = (f32x4){0.f, 0.f, 0.f, 0.f};

    bf16x8 aa[2][2];

    // ---- layer 0: KT=8; wave owns nt = wid*2+{0,1} ----
    {
#pragma unroll
        for (int m = 0; m < 2; ++m)
            aa[0][m] = *(const bf16x8*)&L[(XSB + (m * 16 + lrow) * 512 + ((koff0 * 64 + lkb) ^ swz)) >> 1];
#pragma unroll
        for (int kk = 0; kk < 8; ++kk) {
            const int cur = kk & 1, nxt = cur ^ 1;
            if (kk + 1 < 8) {
                const int kt2 = (koff0 + kk + 1) & 7;
                const u16* src = W0F + (size_t)(e * 8 + kt2) * 16384;
#pragma unroll
                for (int q = 0; q < 2; ++q) {
                    int c = wid * 2 + q;
                    gload16(src + c * 512 + l * 8, L + ((WBB + nxt * 32768 + c * 1024) >> 1));
                }
#pragma unroll
                for (int m = 0; m < 2; ++m)
                    aa[nxt][m] = *(const bf16x8*)&L[(XSB + (m * 16 + lrow) * 512 + ((kt2 * 64 + lkb) ^ swz)) >> 1];
            }
            bf16x8 w0 = *(const bf16x8*)&L[(WBB + cur * 32768 + (wid * 2 + 0) * 1024 + l * 16) >> 1];
            bf16x8 w1 = *(const bf16x8*)&L[(WBB + cur * 32768 + (wid * 2 + 1) * 1024 + l * 16) >> 1];
            __builtin_amdgcn_s_setprio(1);
            acc[0][0] = __builtin_amdgcn_mfma_f32_16x16x32_bf16(aa[cur][0], w0, acc[0][0], 0, 0, 0);
            acc[0][1] = __builtin_amdgcn_mfma_f32_16x16x32_bf16(aa[cur][1], w0, acc[0][1], 0, 0, 0);
            acc[1][0] = __builtin_amdgcn_mfma_f32_16x16x32_bf16(aa[cur][0], w1, acc[1][0], 0, 0, 0);
            acc[1][1] = __builtin_amdgcn_mfma_f32_16x16x32_bf16(aa[cur][1], w1, acc[1][1], 0, 0, 0);
            __builtin_amdgcn_s_setprio(0);
            __syncthreads();                  // drains next-slab DMA; protects dbuf reuse
        }
        // epilogue -> h0
#pragma unroll
        for (int j = 0; j < 2; ++j) {
            int col = (wid * 2 + j) * 16 + lrow;
            float bias = b0[e * NH + col];
#pragma unroll
            for (int m = 0; m < 2; ++m)
#pragma unroll
                for (int r = 0; r < 4; ++r) {
                    int row = m * 16 + (l >> 4) * 4 + r;
                    float tv = fast_tanh(acc[j][m][r] + bias);
                    int bb2 = H0B + row * 1024 + ((col * 2) ^ ((row & 7) << 4));
                    L[bb2 >> 1] = bf16rne(tv);
                }
        }
    }
    // L1 prologue: stage slab(koff1) into WB0, then barrier (h0 visible + slab drained)
    {
        const u16* src = W1F + (size_t)(e * 16 + (koff1 & 15)) * 16384;
#pragma unroll
        for (int q = 0; q < 2; ++q) {
            int c = wid * 2 + q;
            gload16(src + c * 512 + l * 8, L + ((WBB + c * 1024) >> 1));
        }
    }
    __syncthreads();

    // ---- layer 1: KT=16 ----
    {
#pragma unroll
        for (int m = 0; m < 2; ++m)
#pragma unroll
            for (int j = 0; j < 2; ++j) acc[j][m] = (f32x4){0.f, 0.f, 0.f, 0.f};
#pragma unroll
        for (int m = 0; m < 2; ++m)
            aa[0][m] = *(const bf16x8*)&L[(H0B + (m * 16 + lrow) * 1024 + ((koff1 * 64 + lkb) ^ swz)) >> 1];
#pragma unroll
        for (int kk = 0; kk < 16; ++kk) {
            const int cur = kk & 1, nxt = cur ^ 1;
            if (kk + 1 < 16) {
                const int kt2 = (koff1 + kk + 1) & 15;
                const u16* src = W1F + (size_t)(e * 16 + kt2) * 16384;
#pragma unroll
                for (int q = 0; q < 2; ++q) {
                    int c = wid * 2 + q;
                    gload16(src + c * 512 + l * 8, L + ((WBB + nxt * 32768 + c * 1024) >> 1));
                }
#pragma unroll
                for (int m = 0; m < 2; ++m)
                    aa[nxt][m] = *(const bf16x8*)&L[(H0B + (m * 16 + lrow) * 1024 + ((kt2 * 64 + lkb) ^ swz)) >> 1];
            }
            bf16x8 w0 = *(const bf16x8*)&L[(WBB + cur * 32768 + (wid * 2 + 0) * 1024 + l * 16) >> 1];
            bf16x8 w1 = *(const bf16x8*)&L[(WBB + cur * 32768 + (wid * 2 + 1) * 1024 + l * 16) >> 1];
            __builtin_amdgcn_s_setprio(1);
            acc[0][0] = __builtin_amdgcn_mfma_f32_16x16x32_bf16(aa[cur][0], w0, acc[0][0], 0, 0, 0);
            acc[0][1] = __builtin_amdgcn_mfma_f32_16x16x32_bf16(aa[cur][1], w0, acc[0][1], 0, 0, 0);
            acc[1][0] = __builtin_amdgcn_mfma_f32_16x16x32_bf16(aa[cur][0], w1, acc[1][0], 0, 0, 0);
            acc[1][1] = __builtin_amdgcn_mfma_f32_16x16x32_bf16(aa[cur][1], w1, acc[1][1], 0, 0, 0);
            __builtin_amdgcn_s_setprio(0);
            __syncthreads();
        }
        // epilogue -> h1
#pragma unroll
        for (int j = 0; j < 2; ++j) {
            int col = (wid * 2 + j) * 16 + lrow;
            float bias = b1[e * NH + col];
#pragma unroll
            for (int m = 0; m < 2; ++m)
#pragma unroll
                for (int r = 0; r < 4; ++r) {
                    int row = m * 16 + (l >> 4) * 4 + r;
                    float tv = fast_tanh(acc[j][m][r] + bias);
                    int bb2 = H1B + row * 1024 + ((col * 2) ^ ((row & 7) << 4));
                    L[bb2 >> 1] = bf16rne(tv);
                }
        }
    }
    // L2 prologue: stage ALL of Wo[e] (64KB) into WB region
    {
        const u16* src = WoF + (size_t)e * (16 * 2048);
#pragma unroll
        for (int q = 0; q < 4; ++q) {
            int c = wid * 4 + q;
            gload16(src + c * 512 + l * 8, L + ((WBB + c * 1024) >> 1));
        }
    }
    __syncthreads();

    // ---- layer 2: out = h1 @ Wo + bo; 8 waves (nt = wid&3, mt = wid>>2), no barriers ----
    if (wid < 8) {
        const int nt = wid & 3, mt = wid >> 2;
        f32x4 a2 = (f32x4){0.f, 0.f, 0.f, 0.f};
#pragma unroll
        for (int kt = 0; kt < 16; ++kt) {
            bf16x8 wa = *(const bf16x8*)&L[(H1B + (mt * 16 + lrow) * 1024 + ((kt * 64 + lkb) ^ swz)) >> 1];
            bf16x8 wb = *(const bf16x8*)&L[(WBB + kt * 4096 + nt * 1024 + l * 16) >> 1];
            a2 = __builtin_amdgcn_mfma_f32_16x16x32_bf16(wa, wb, a2, 0, 0, 0);
        }
        int col = nt * 16 + lrow;
        float bias = bo[e * NO + col];
#pragma unroll
        for (int r = 0; r < 4; ++r) {
            int row = mt * 16 + (l >> 4) * 4 + r;
            int g = rows_s[row];
            if (g >= 0) out[(size_t)g * NO + col] = a2[r] + bias;
        }
    }
}

extern "C" void kernel_launch(void* const* d_in, const int* in_sizes, int n_in,
                              void* d_out, int out_size, void* d_ws, size_t ws_size,
                              hipStream_t stream) {
    const float* x  = (const float*)d_in[0];
    const float* W0 = (const float*)d_in[1];
    const float* b0 = (const float*)d_in[2];
    const float* W1 = (const float*)d_in[3];
    const float* b1 = (const float*)d_in[4];
    const float* Wo = (const float*)d_in[5];
    const float* bo = (const float*)d_in[6];
    float* out = (float*)d_out;
    int* wsI = (int*)d_ws;
    u16* W0F = (u16*)((char*)d_ws + (512 << 10));
    u16* W1F = W0F + (size_t)NK * ND * NH;
    u16* WoF = W1F + (size_t)NK * NH * NH;

    hipMemsetAsync(wsI, 0, 64, stream);     // counts
    prep_kernel<<<352, 256, 0, stream>>>(x, W0, W1, Wo, wsI, W0F, W1F, WoF);
    mlp_kernel<<<NK * TILES_MAX, 1024, 0, stream>>>(x, b0, b1, bo, wsI, W0F, W1F, WoF, out);
}